// Round 1
// baseline (92.323 us; speedup 1.0000x reference)
//
#include <hip/hip_runtime.h>
#include <stdint.h>

// VarifoldKernel: out[b] = sum_{n,m} w1[b,n]*w2[b,m]*exp(-2*||p1-p2||^2)*exp(-f1.f2/2)
// Log-space: term = 2^( dot(A1[n], A2[m]) ) where K=80-padded rows carry
//   A1 = [2*pos1, 0, feat1,            la1_hi, la1_lo, 1, 1, 0x8]   (fp16)
//   A2 = [2*L*pos2, 0, -0.5*L*feat2,   1, 1, la2_hi, la2_lo, 0x8]   (fp16)
//   la = clamp(log2(w) - 2*L*|pos|^2, >= -1000), hi/lo fp16 split, L = log2(e)
// R7: switch 16x16x32 (K=96, 25% zero-pad) -> 32x32x16 (K=80): -17% MFMA work at a
// ~11% faster shape; register diet (bf[5][2]=40 + af[5]=20 + 2x16 acc = ~105 VGPR,
// off the 128 cliff); prefetch folded into af[] reload between MFMA and epilogue.

typedef _Float16 f16;
typedef _Float16 v8h  __attribute__((ext_vector_type(8)));
typedef _Float16 h4   __attribute__((ext_vector_type(4)));
typedef float    v16f __attribute__((ext_vector_type(16)));

#define L2E 1.4426950408889634f
#define BN 4096
#define KP 80    // padded K (halfs); row = 160 B

// ---------------- prep: fp32 -> fp16 U matrices (log terms folded into K-pad) -------
__global__ __launch_bounds__(256) void prep_kernel(
    const float* __restrict__ pos1, const float* __restrict__ feat1, const float* __restrict__ w1,
    const float* __restrict__ pos2, const float* __restrict__ feat2, const float* __restrict__ w2,
    f16* __restrict__ U1, f16* __restrict__ U2)
{
    int tid  = threadIdx.x;
    int ridx = blockIdx.x * 16 + (tid >> 4);   // 0..32767
    int c    = tid & 15;
    int side = ridx >> 14;                     // 0: side1, 1: side2
    int idx  = ridx & 16383;                   // b*4096 + row

    const float* feat = side ? feat2 : feat1;
    f16* U   = side ? U2 : U1;
    float fs = side ? -0.5f * L2E : 1.0f;

    // feat -> halfs 4..67 (c-th float4 -> h4 at 4+4c), coalesced
    float4 v = ((const float4*)feat)[idx * 16 + c];
    *(h4*)(U + (long)idx * KP + 4 + c * 4) =
        h4{(f16)(v.x * fs), (f16)(v.y * fs), (f16)(v.z * fs), (f16)(v.w * fs)};

    if (c == 0) {
        const float* pos = side ? pos2 : pos1;
        const float* w   = side ? w2   : w1;
        float ps  = side ? 2.0f * L2E : 2.0f;
        float p0 = pos[idx*3+0], p1 = pos[idx*3+1], p2 = pos[idx*3+2];
        // log-space row term, clamped so w==0 can't yield -inf (then lo would be NaN)
        float la = __builtin_amdgcn_logf(w[idx]) - 2.0f * L2E * (p0*p0 + p1*p1 + p2*p2);
        la = fmaxf(la, -1000.0f);
        f16   hi = (f16)la;
        f16   lo = (f16)(la - (float)hi);
        *(h4*)(U + (long)idx * KP) = h4{(f16)(p0*ps), (f16)(p1*ps), (f16)(p2*ps), (f16)0.0f};
        // k68..71: A-side carries {la1_hi, la1_lo, 1, 1}; B-side {1, 1, la2_hi, la2_lo}
        *(h4*)(U + (long)idx * KP + 68) =
            side ? h4{(f16)1.0f, (f16)1.0f, hi, lo}
                 : h4{hi, lo, (f16)1.0f, (f16)1.0f};
    } else if (c <= 2) {
        // k72..79 zero (2 x h4)
        *(h4*)(U + (long)idx * KP + 72 + (c - 1) * 4) =
            h4{(f16)0.0f, (f16)0.0f, (f16)0.0f, (f16)0.0f};
    }
}

// ---------------- main: barrier-free, register-persistent B stripe, 32x32x16 --------
// Block = 4 waves. Wave w owns cols [stripe*256 + w*64, +64) for a 256-row chunk
// (8 tiles of 32 rows). B frags persist in registers; A frags reloaded per tile with
// the reload issued between the MFMA chain and the exp2 epilogue (1-tile prefetch
// without a second register set). Epilogue: psum += exp2(acc) — la terms already
// inside the accumulator.
__global__ __launch_bounds__(256, 4) void varifold_kernel(
    const f16* __restrict__ U1, const f16* __restrict__ U2,
    float* __restrict__ pw)
{
    int tid = threadIdx.x, wave = tid >> 6, lane = tid & 63;
    int stripe = blockIdx.x, nchunk = blockIdx.y, b = blockIdx.z;
    int l31 = lane & 31, kh = lane >> 5;       // row/col in tile, k-half select

    long colr = (long)b*BN + stripe*256 + wave*64;   // this wave's first col row-index
    long row0 = (long)b*BN + nchunk*256;             // this block's first row

    // --- persistent B fragments (registers for whole kernel): 2 col-groups x 5 K-chunks
    v8h bf[5][2];
    #pragma unroll
    for (int j = 0; j < 2; ++j) {
        const f16* r = U2 + (colr + j*32 + l31) * KP + kh*8;
        #pragma unroll
        for (int c = 0; c < 5; ++c) bf[c][j] = *(const v8h*)(r + c*16);
    }

    const f16* Ab = U1 + (row0 + l31) * KP + kh*8;   // A frag base (+32 rows/tile)
    v8h af[5];
    #pragma unroll
    for (int c = 0; c < 5; ++c) af[c] = *(const v8h*)(Ab + c*16);

    float ps0 = 0.f, ps1 = 0.f;
    #pragma unroll 2
    for (int t = 0; t < 8; ++t) {
        v16f acc0 = {0.f,0.f,0.f,0.f,0.f,0.f,0.f,0.f,0.f,0.f,0.f,0.f,0.f,0.f,0.f,0.f};
        v16f acc1 = {0.f,0.f,0.f,0.f,0.f,0.f,0.f,0.f,0.f,0.f,0.f,0.f,0.f,0.f,0.f,0.f};
        #pragma unroll
        for (int c = 0; c < 5; ++c) {
            acc0 = __builtin_amdgcn_mfma_f32_32x32x16_f16(af[c], bf[c][0], acc0, 0, 0, 0);
            acc1 = __builtin_amdgcn_mfma_f32_32x32x16_f16(af[c], bf[c][1], acc1, 0, 0, 0);
        }

        // reload af[] for the next tile now (clamped; last iter re-loads self) —
        // the loads fly while the exp2 epilogue runs, and are waited on only at the
        // next tile's first MFMA.
        const f16* An = Ab + (long)((t < 7) ? (t + 1) : t) * 32 * KP;
        #pragma unroll
        for (int c = 0; c < 5; ++c) af[c] = *(const v8h*)(An + c*16);

        // epilogue: accumulator already holds dot + la1 + la2; sum-all is C/D-layout
        // invariant. Two psum chains to halve the serial-add dependency.
        #pragma unroll
        for (int j = 0; j < 16; ++j) {
            ps0 += __builtin_amdgcn_exp2f(acc0[j]);
            ps1 += __builtin_amdgcn_exp2f(acc1[j]);
        }
    }
    float psum = ps0 + ps1;

    // --- wave reduce -> one plain store per wave (no atomics, no LDS) ---
    #pragma unroll
    for (int off = 32; off > 0; off >>= 1) psum += __shfl_down(psum, off);
    if (lane == 0)
        pw[(((long)b*16 + nchunk)*16 + stripe)*4 + wave] = psum;
}

// ---------------- final: reduce 1024 partials per batch -> out[b] -------------------
__global__ __launch_bounds__(256) void reduce_kernel(
    const float* __restrict__ pw, float* __restrict__ out)
{
    __shared__ float sred[4];
    int b = blockIdx.x, tid = threadIdx.x;
    const float* p = pw + (long)b * 1024;
    float v = p[tid] + p[tid + 256] + p[tid + 512] + p[tid + 768];
    #pragma unroll
    for (int off = 32; off > 0; off >>= 1) v += __shfl_down(v, off);
    if ((tid & 63) == 0) sred[tid >> 6] = v;
    __syncthreads();
    if (tid == 0) out[b] = sred[0] + sred[1] + sred[2] + sred[3];
}

extern "C" void kernel_launch(void* const* d_in, const int* in_sizes, int n_in,
                              void* d_out, int out_size, void* d_ws, size_t ws_size,
                              hipStream_t stream) {
    const float* pos1  = (const float*)d_in[0];
    const float* feat1 = (const float*)d_in[1];
    const float* w1    = (const float*)d_in[2];
    const float* pos2  = (const float*)d_in[3];
    const float* feat2 = (const float*)d_in[4];
    const float* w2    = (const float*)d_in[5];
    float* out = (float*)d_out;

    // workspace layout (5,259,264 B)
    char* ws = (char*)d_ws;
    f16*   U1  = (f16*)(ws);                          // 16384 rows * 80 halfs = 2,621,440
    f16*   U2  = (f16*)(ws + 2621440);                // 2,621,440
    float* pw  = (float*)(ws + 5242880);              // 4096 * 4 = 16,384

    prep_kernel<<<2048, 256, 0, stream>>>(pos1, feat1, w1, pos2, feat2, w2, U1, U2);
    dim3 grid(16, 16, 4);  // (stripe, nchunk, b) — stripe fastest for A-row L2 locality
    varifold_kernel<<<grid, 256, 0, stream>>>(U1, U2, pw);
    reduce_kernel<<<4, 256, 0, stream>>>(pw, out);
}

// Round 2
// 88.179 us; speedup vs baseline: 1.0470x; 1.0470x over previous
//
#include <hip/hip_runtime.h>
#include <stdint.h>

// VarifoldKernel: out[b] = sum_{n,m} w1[b,n]*w2[b,m]*exp(-2*||p1-p2||^2)*exp(-f1.f2/2)
// Log-space: term = 2^( dot(A1[n], A2[m]) ) where K=80-padded rows carry
//   A1 = [2*pos1, 0, feat1,            la1_hi, la1_lo, 1, 1, 0x8]   (fp16)
//   A2 = [2*L*pos2, 0, -0.5*L*feat2,   1, 1, la2_hi, la2_lo, 0x8]   (fp16)
//   la = clamp(log2(w) - 2*L*|pos|^2, >= -1000), hi/lo fp16 split, L = log2(e)
// R8 = R7 with the register cliff removed: #pragma unroll 1 on the tile loop
// (unroll 2 kept two iterations' acc+prefetch live -> >128 VGPR under
// __launch_bounds__(256,4) -> scratch spills in the hot loop). Est ~114 VGPR now.

typedef _Float16 f16;
typedef _Float16 v8h  __attribute__((ext_vector_type(8)));
typedef _Float16 h4   __attribute__((ext_vector_type(4)));
typedef float    v16f __attribute__((ext_vector_type(16)));

#define L2E 1.4426950408889634f
#define BN 4096
#define KP 80    // padded K (halfs); row = 160 B

// ---------------- prep: fp32 -> fp16 U matrices (log terms folded into K-pad) -------
__global__ __launch_bounds__(256) void prep_kernel(
    const float* __restrict__ pos1, const float* __restrict__ feat1, const float* __restrict__ w1,
    const float* __restrict__ pos2, const float* __restrict__ feat2, const float* __restrict__ w2,
    f16* __restrict__ U1, f16* __restrict__ U2)
{
    int tid  = threadIdx.x;
    int ridx = blockIdx.x * 16 + (tid >> 4);   // 0..32767
    int c    = tid & 15;
    int side = ridx >> 14;                     // 0: side1, 1: side2
    int idx  = ridx & 16383;                   // b*4096 + row

    const float* feat = side ? feat2 : feat1;
    f16* U   = side ? U2 : U1;
    float fs = side ? -0.5f * L2E : 1.0f;

    // feat -> halfs 4..67 (c-th float4 -> h4 at 4+4c), coalesced
    float4 v = ((const float4*)feat)[idx * 16 + c];
    *(h4*)(U + (long)idx * KP + 4 + c * 4) =
        h4{(f16)(v.x * fs), (f16)(v.y * fs), (f16)(v.z * fs), (f16)(v.w * fs)};

    if (c == 0) {
        const float* pos = side ? pos2 : pos1;
        const float* w   = side ? w2   : w1;
        float ps  = side ? 2.0f * L2E : 2.0f;
        float p0 = pos[idx*3+0], p1 = pos[idx*3+1], p2 = pos[idx*3+2];
        // log-space row term, clamped so w==0 can't yield -inf (then lo would be NaN)
        float la = __builtin_amdgcn_logf(w[idx]) - 2.0f * L2E * (p0*p0 + p1*p1 + p2*p2);
        la = fmaxf(la, -1000.0f);
        f16   hi = (f16)la;
        f16   lo = (f16)(la - (float)hi);
        *(h4*)(U + (long)idx * KP) = h4{(f16)(p0*ps), (f16)(p1*ps), (f16)(p2*ps), (f16)0.0f};
        // k68..71: A-side carries {la1_hi, la1_lo, 1, 1}; B-side {1, 1, la2_hi, la2_lo}
        *(h4*)(U + (long)idx * KP + 68) =
            side ? h4{(f16)1.0f, (f16)1.0f, hi, lo}
                 : h4{hi, lo, (f16)1.0f, (f16)1.0f};
    } else if (c <= 2) {
        // k72..79 zero (2 x h4)
        *(h4*)(U + (long)idx * KP + 72 + (c - 1) * 4) =
            h4{(f16)0.0f, (f16)0.0f, (f16)0.0f, (f16)0.0f};
    }
}

// ---------------- main: barrier-free, register-persistent B stripe, 32x32x16 --------
// Block = 4 waves. Wave w owns cols [stripe*256 + w*64, +64) for a 256-row chunk
// (8 tiles of 32 rows). B frags persist in registers; A frags reloaded per tile,
// reload issued between the MFMA chain and the exp2 epilogue (1-tile prefetch
// without a second register set). unroll 1: keeps live set ~114 VGPR (<128 cap).
__global__ __launch_bounds__(256, 4) void varifold_kernel(
    const f16* __restrict__ U1, const f16* __restrict__ U2,
    float* __restrict__ pw)
{
    int tid = threadIdx.x, wave = tid >> 6, lane = tid & 63;
    int stripe = blockIdx.x, nchunk = blockIdx.y, b = blockIdx.z;
    int l31 = lane & 31, kh = lane >> 5;       // row/col in tile, k-half select

    long colr = (long)b*BN + stripe*256 + wave*64;   // this wave's first col row-index
    long row0 = (long)b*BN + nchunk*256;             // this block's first row

    // --- persistent B fragments (registers for whole kernel): 2 col-groups x 5 K-chunks
    v8h bf[5][2];
    #pragma unroll
    for (int j = 0; j < 2; ++j) {
        const f16* r = U2 + (colr + j*32 + l31) * KP + kh*8;
        #pragma unroll
        for (int c = 0; c < 5; ++c) bf[c][j] = *(const v8h*)(r + c*16);
    }

    const f16* Ab = U1 + (row0 + l31) * KP + kh*8;   // A frag base (+32 rows/tile)
    v8h af[5];
    #pragma unroll
    for (int c = 0; c < 5; ++c) af[c] = *(const v8h*)(Ab + c*16);

    float ps0 = 0.f, ps1 = 0.f, ps2 = 0.f, ps3 = 0.f;
    #pragma unroll 1
    for (int t = 0; t < 8; ++t) {
        v16f acc0 = {0.f,0.f,0.f,0.f,0.f,0.f,0.f,0.f,0.f,0.f,0.f,0.f,0.f,0.f,0.f,0.f};
        v16f acc1 = {0.f,0.f,0.f,0.f,0.f,0.f,0.f,0.f,0.f,0.f,0.f,0.f,0.f,0.f,0.f,0.f};
        #pragma unroll
        for (int c = 0; c < 5; ++c) {
            acc0 = __builtin_amdgcn_mfma_f32_32x32x16_f16(af[c], bf[c][0], acc0, 0, 0, 0);
            acc1 = __builtin_amdgcn_mfma_f32_32x32x16_f16(af[c], bf[c][1], acc1, 0, 0, 0);
        }

        // reload af[] for the next tile now (clamped; last iter re-loads self) —
        // loads fly while the exp2 epilogue runs, waited on at next tile's MFMAs.
        const f16* An = Ab + (long)((t < 7) ? (t + 1) : t) * 32 * KP;
        #pragma unroll
        for (int c = 0; c < 5; ++c) af[c] = *(const v8h*)(An + c*16);

        // epilogue: accumulator already holds dot + la1 + la2; sum-all is C/D-layout
        // invariant. Four psum chains to keep the serial-add dependency short.
        #pragma unroll
        for (int j = 0; j < 16; j += 2) {
            ps0 += __builtin_amdgcn_exp2f(acc0[j]);
            ps1 += __builtin_amdgcn_exp2f(acc0[j+1]);
            ps2 += __builtin_amdgcn_exp2f(acc1[j]);
            ps3 += __builtin_amdgcn_exp2f(acc1[j+1]);
        }
    }
    float psum = (ps0 + ps1) + (ps2 + ps3);

    // --- wave reduce -> one plain store per wave (no atomics, no LDS) ---
    #pragma unroll
    for (int off = 32; off > 0; off >>= 1) psum += __shfl_down(psum, off);
    if (lane == 0)
        pw[(((long)b*16 + nchunk)*16 + stripe)*4 + wave] = psum;
}

// ---------------- final: reduce 1024 partials per batch -> out[b] -------------------
__global__ __launch_bounds__(256) void reduce_kernel(
    const float* __restrict__ pw, float* __restrict__ out)
{
    __shared__ float sred[4];
    int b = blockIdx.x, tid = threadIdx.x;
    const float* p = pw + (long)b * 1024;
    float v = p[tid] + p[tid + 256] + p[tid + 512] + p[tid + 768];
    #pragma unroll
    for (int off = 32; off > 0; off >>= 1) v += __shfl_down(v, off);
    if ((tid & 63) == 0) sred[tid >> 6] = v;
    __syncthreads();
    if (tid == 0) out[b] = sred[0] + sred[1] + sred[2] + sred[3];
}

extern "C" void kernel_launch(void* const* d_in, const int* in_sizes, int n_in,
                              void* d_out, int out_size, void* d_ws, size_t ws_size,
                              hipStream_t stream) {
    const float* pos1  = (const float*)d_in[0];
    const float* feat1 = (const float*)d_in[1];
    const float* w1    = (const float*)d_in[2];
    const float* pos2  = (const float*)d_in[3];
    const float* feat2 = (const float*)d_in[4];
    const float* w2    = (const float*)d_in[5];
    float* out = (float*)d_out;

    // workspace layout (5,259,264 B)
    char* ws = (char*)d_ws;
    f16*   U1  = (f16*)(ws);                          // 16384 rows * 80 halfs = 2,621,440
    f16*   U2  = (f16*)(ws + 2621440);                // 2,621,440
    float* pw  = (float*)(ws + 5242880);              // 4096 * 4 = 16,384

    prep_kernel<<<2048, 256, 0, stream>>>(pos1, feat1, w1, pos2, feat2, w2, U1, U2);
    dim3 grid(16, 16, 4);  // (stripe, nchunk, b) — stripe fastest for A-row L2 locality
    varifold_kernel<<<grid, 256, 0, stream>>>(U1, U2, pw);
    reduce_kernel<<<4, 256, 0, stream>>>(pw, out);
}

// Round 3
// 85.547 us; speedup vs baseline: 1.0792x; 1.0308x over previous
//
#include <hip/hip_runtime.h>
#include <stdint.h>

// VarifoldKernel: out[b] = sum_{n,m} w1[b,n]*w2[b,m]*exp(-2*||p1-p2||^2)*exp(-f1.f2/2)
// Log-space: term = 2^( dot(A1[n], A2[m]) ) where K=80-padded rows carry
//   A1 = [2*pos1, 0, feat1,            la1_hi, la1_lo, 1, 1, 0x8]   (fp16)
//   A2 = [2*L*pos2, 0, -0.5*L*feat2,   1, 1, la2_hi, la2_lo, 0x8]   (fp16)
//   la = clamp(log2(w) - 2*L*|pos|^2, >= -1000), hi/lo fp16 split, L = log2(e)
//
// R9 = R8 math + FRAGMENT-MAJOR GLOBAL LAYOUT (pre-swizzled, m173 pattern).
// Old layout: row-major KP=80 -> every fragment load had per-lane addresses
// striding 160 B => ~32-64 cache-line transactions per global_load_dwordx4
// (address-divergence bound, invariant across R6/R7/R8 - explains the nulls).
// New layout: U stored as 32-row groups; within a group 10 chunks (c=0..4, kh=0..1),
// each chunk = 32 lanes x 8 halfs contiguous:
//   addr(half) = group*2560 + (c*2+kh)*256 + l31*8 + off
// A wave's fragment load (lanes (l31,kh)) is now 1 KB fully contiguous.

typedef _Float16 f16;
typedef _Float16 v8h  __attribute__((ext_vector_type(8)));
typedef _Float16 h4   __attribute__((ext_vector_type(4)));
typedef float    v16f __attribute__((ext_vector_type(16)));

#define L2E 1.4426950408889634f
#define BN 4096
#define GH 2560   // halfs per 32-row group (32 rows * 80 halfs)

// ---------------- prep: fp32 -> fp16 U (fragment-major layout) ----------------------
__global__ __launch_bounds__(256) void prep_kernel(
    const float* __restrict__ pos1, const float* __restrict__ feat1, const float* __restrict__ w1,
    const float* __restrict__ pos2, const float* __restrict__ feat2, const float* __restrict__ w2,
    f16* __restrict__ U1, f16* __restrict__ U2)
{
    int tid  = threadIdx.x;
    int ridx = blockIdx.x * 16 + (tid >> 4);   // 0..32767
    int c    = tid & 15;
    int side = ridx >> 14;                     // 0: side1, 1: side2
    int idx  = ridx & 16383;                   // b*4096 + row

    const float* feat = side ? feat2 : feat1;
    f16* U   = side ? U2 : U1;
    float fs = side ? -0.5f * L2E : 1.0f;

    // this row's base in the swizzled layout: group (idx>>5), lane-slot (idx&31)
    f16* gb = U + (long)(idx >> 5) * GH + (idx & 31) * 8;
    // half-index k0 within the logical 80-half row maps to gb + (k0>>3)*256 + (k0&7)

    // feat -> halfs 4..67 (c-th float4 -> h4 at k0 = 4+4c); k0&7 is 4 or 0, so each
    // h4 lands wholly inside one 8-half chunk.
    float4 v = ((const float4*)feat)[idx * 16 + c];
    int k0 = 4 + 4 * c;
    *(h4*)(gb + (k0 >> 3) * 256 + (k0 & 7)) =
        h4{(f16)(v.x * fs), (f16)(v.y * fs), (f16)(v.z * fs), (f16)(v.w * fs)};

    if (c == 0) {
        const float* pos = side ? pos2 : pos1;
        const float* w   = side ? w2   : w1;
        float ps  = side ? 2.0f * L2E : 2.0f;
        float p0 = pos[idx*3+0], p1 = pos[idx*3+1], p2 = pos[idx*3+2];
        // log-space row term, clamped so w==0 can't yield -inf (then lo would be NaN)
        float la = __builtin_amdgcn_logf(w[idx]) - 2.0f * L2E * (p0*p0 + p1*p1 + p2*p2);
        la = fmaxf(la, -1000.0f);
        f16   hi = (f16)la;
        f16   lo = (f16)(la - (float)hi);
        // k0=0..3: pos (+ zero pad)
        *(h4*)(gb) = h4{(f16)(p0*ps), (f16)(p1*ps), (f16)(p2*ps), (f16)0.0f};
        // k0=68..71: A-side {la_hi, la_lo, 1, 1}; B-side {1, 1, la_hi, la_lo}
        *(h4*)(gb + 8 * 256 + 4) =
            side ? h4{(f16)1.0f, (f16)1.0f, hi, lo}
                 : h4{hi, lo, (f16)1.0f, (f16)1.0f};
    } else if (c <= 2) {
        // k0 = 72, 76: zero tail
        int kz = 68 + 4 * c;
        *(h4*)(gb + (kz >> 3) * 256 + (kz & 7)) =
            h4{(f16)0.0f, (f16)0.0f, (f16)0.0f, (f16)0.0f};
    }
}

// ---------------- main: barrier-free, register-persistent B stripe, 32x32x16 --------
// Block = 4 waves. Wave w owns cols [stripe*256 + w*64, +64) for a 256-row chunk
// (8 tiles of 32 rows = 8 groups). B frags persist in registers; A frags reloaded
// per tile, reload issued between the MFMA chain and the exp2 epilogue.
// All fragment loads are now 1 KB contiguous per wave (fragment-major U).
__global__ __launch_bounds__(256, 4) void varifold_kernel(
    const f16* __restrict__ U1, const f16* __restrict__ U2,
    float* __restrict__ pw)
{
    int tid = threadIdx.x, wave = tid >> 6, lane = tid & 63;
    int stripe = blockIdx.x, nchunk = blockIdx.y, b = blockIdx.z;
    int l31 = lane & 31, kh = lane >> 5;       // row/col in tile, k-half select

    // per-wave fragment bases (all further offsets are compile-time constants)
    const f16* B0 = U2 + (long)(b*128 + stripe*8 + wave*2) * GH + kh*256 + l31*8;
    const f16* A0 = U1 + (long)(b*128 + nchunk*8)          * GH + kh*256 + l31*8;

    // --- persistent B fragments (registers for whole kernel): 2 col-groups x 5 K-chunks
    v8h bf[5][2];
    #pragma unroll
    for (int j = 0; j < 2; ++j)
        #pragma unroll
        for (int c = 0; c < 5; ++c)
            bf[c][j] = *(const v8h*)(B0 + j*GH + c*512);

    v8h af[5];
    #pragma unroll
    for (int c = 0; c < 5; ++c) af[c] = *(const v8h*)(A0 + c*512);

    float ps0 = 0.f, ps1 = 0.f, ps2 = 0.f, ps3 = 0.f;
    #pragma unroll 1
    for (int t = 0; t < 8; ++t) {
        v16f acc0 = {0.f,0.f,0.f,0.f,0.f,0.f,0.f,0.f,0.f,0.f,0.f,0.f,0.f,0.f,0.f,0.f};
        v16f acc1 = {0.f,0.f,0.f,0.f,0.f,0.f,0.f,0.f,0.f,0.f,0.f,0.f,0.f,0.f,0.f,0.f};
        #pragma unroll
        for (int c = 0; c < 5; ++c) {
            acc0 = __builtin_amdgcn_mfma_f32_32x32x16_f16(af[c], bf[c][0], acc0, 0, 0, 0);
            acc1 = __builtin_amdgcn_mfma_f32_32x32x16_f16(af[c], bf[c][1], acc1, 0, 0, 0);
        }

        // reload af[] for the next tile now (clamped; last iter re-loads self) —
        // loads fly while the exp2 epilogue runs, waited on at next tile's MFMAs.
        const f16* An = A0 + (long)((t < 7) ? (t + 1) : t) * GH;
        #pragma unroll
        for (int c = 0; c < 5; ++c) af[c] = *(const v8h*)(An + c*512);

        // epilogue: accumulator already holds dot + la1 + la2; sum-all is C/D-layout
        // invariant. Four psum chains to keep the serial-add dependency short.
        #pragma unroll
        for (int j = 0; j < 16; j += 2) {
            ps0 += __builtin_amdgcn_exp2f(acc0[j]);
            ps1 += __builtin_amdgcn_exp2f(acc0[j+1]);
            ps2 += __builtin_amdgcn_exp2f(acc1[j]);
            ps3 += __builtin_amdgcn_exp2f(acc1[j+1]);
        }
    }
    float psum = (ps0 + ps1) + (ps2 + ps3);

    // --- wave reduce -> one plain store per wave (no atomics, no LDS) ---
    #pragma unroll
    for (int off = 32; off > 0; off >>= 1) psum += __shfl_down(psum, off);
    if (lane == 0)
        pw[(((long)b*16 + nchunk)*16 + stripe)*4 + wave] = psum;
}

// ---------------- final: reduce 1024 partials per batch -> out[b] -------------------
__global__ __launch_bounds__(256) void reduce_kernel(
    const float* __restrict__ pw, float* __restrict__ out)
{
    __shared__ float sred[4];
    int b = blockIdx.x, tid = threadIdx.x;
    const float* p = pw + (long)b * 1024;
    float v = p[tid] + p[tid + 256] + p[tid + 512] + p[tid + 768];
    #pragma unroll
    for (int off = 32; off > 0; off >>= 1) v += __shfl_down(v, off);
    if ((tid & 63) == 0) sred[tid >> 6] = v;
    __syncthreads();
    if (tid == 0) out[b] = sred[0] + sred[1] + sred[2] + sred[3];
}

extern "C" void kernel_launch(void* const* d_in, const int* in_sizes, int n_in,
                              void* d_out, int out_size, void* d_ws, size_t ws_size,
                              hipStream_t stream) {
    const float* pos1  = (const float*)d_in[0];
    const float* feat1 = (const float*)d_in[1];
    const float* w1    = (const float*)d_in[2];
    const float* pos2  = (const float*)d_in[3];
    const float* feat2 = (const float*)d_in[4];
    const float* w2    = (const float*)d_in[5];
    float* out = (float*)d_out;

    // workspace layout (5,259,264 B)
    char* ws = (char*)d_ws;
    f16*   U1  = (f16*)(ws);                          // 512 groups * 2560 halfs = 2,621,440 B
    f16*   U2  = (f16*)(ws + 2621440);                // 2,621,440 B
    float* pw  = (float*)(ws + 5242880);              // 4096 * 4 = 16,384 B

    prep_kernel<<<2048, 256, 0, stream>>>(pos1, feat1, w1, pos2, feat2, w2, U1, U2);
    dim3 grid(16, 16, 4);  // (stripe, nchunk, b) — stripe fastest for A-row L2 locality
    varifold_kernel<<<grid, 256, 0, stream>>>(U1, U2, pw);
    reduce_kernel<<<4, 256, 0, stream>>>(pw, out);
}